// Round 1
// baseline (592.756 us; speedup 1.0000x reference)
//
#include <hip/hip_runtime.h>

#define NB 128
#define SSEQ 1024
#define TD 512
#define NSPLIT 8

typedef _Float16 half8 __attribute__((ext_vector_type(8)));
typedef _Float16 half4 __attribute__((ext_vector_type(4)));
typedef float f32x4 __attribute__((ext_vector_type(4)));

// ---------------- K0: fp32 -> fp16 conversions (fused, vec4) ----------------
__global__ __launch_bounds__(256) void k_cvt(
    const float* __restrict__ v, const float* __restrict__ w1,
    const float* __restrict__ w2, const float* __restrict__ wq,
    const float* __restrict__ wv, const float* __restrict__ wo,
    _Float16* __restrict__ v16, _Float16* __restrict__ w1h,
    _Float16* __restrict__ w2h, _Float16* __restrict__ wqh,
    _Float16* __restrict__ wvh, _Float16* __restrict__ woh)
{
  int i = blockIdx.x * 256 + threadIdx.x;   // vec4 index
  const float* src; _Float16* dst; long j;
  if      (i < 294912)  { src = v;  dst = v16; j = i; }
  else if (i < 393216)  { src = w1; dst = w1h; j = i - 294912; }
  else if (i < 1179648) { src = w2; dst = w2h; j = i - 393216; }
  else if (i < 1245184) { src = wq; dst = wqh; j = i - 1179648; }
  else if (i < 1310720) { src = wv; dst = wvh; j = i - 1245184; }
  else if (i < 1376256) { src = wo; dst = woh; j = i - 1310720; }
  else return;
  f32x4 x = *(const f32x4*)(src + 4 * j);
  *(half4*)(dst + 4 * j) = __builtin_convertvector(x, half4);
}

// ---------------- generic NT GEMM, fp16 MFMA, fp32 accum ----------------
// C[m][n] = sum_k A[m][k]*B[n][k]; 64x64 tile, 4 waves (wave w = rows 16w..16w+15)
// outMode: 0 = fp32 store, 1 = fp16 store, 2 = fp32 atomicAdd (split-K)
__global__ __launch_bounds__(256) void k_gemm(
    const _Float16* __restrict__ A, int lda, long aSZ,
    const _Float16* __restrict__ B, int ldb, long bSZ,
    const float* __restrict__ bias, float scale, int doRelu, int outMode,
    float* __restrict__ outF, _Float16* __restrict__ outH,
    int ldc, int cColOff, int mtiles, int kTiles)
{
  __shared__ _Float16 As[64][72];   // 72-halfs row stride: 16B-aligned rows, conflict-safe
  __shared__ _Float16 Bs[64][72];
  int mt = blockIdx.x % mtiles, nt = blockIdx.x / mtiles;
  int sp = blockIdx.y, bz = blockIdx.z;
  int tid = threadIdx.x;
  int r = tid >> 2, kq = (tid & 3) * 16;
  int w = tid >> 6, l = tid & 63;
  const _Float16* Ab = A + (long)bz * aSZ + (long)(mt * 64) * lda + (long)sp * kTiles * 64;
  const _Float16* Bb = B + (long)bz * bSZ + (long)(nt * 64) * ldb + (long)sp * kTiles * 64;
  const _Float16* ap = Ab + (long)r * lda + kq;
  const _Float16* bp = Bb + (long)r * ldb + kq;
  half8 ag0 = *(const half8*)ap, ag1 = *(const half8*)(ap + 8);
  half8 bg0 = *(const half8*)bp, bg1 = *(const half8*)(bp + 8);
  f32x4 acc[4];
  #pragma unroll
  for (int c = 0; c < 4; ++c) acc[c] = (f32x4){0.f, 0.f, 0.f, 0.f};
  int fr = l & 15, fo = (l >> 4) * 8;
  for (int kt = 0; kt < kTiles; ++kt) {
    __syncthreads();
    *(half8*)&As[r][kq] = ag0; *(half8*)&As[r][kq + 8] = ag1;
    *(half8*)&Bs[r][kq] = bg0; *(half8*)&Bs[r][kq + 8] = bg1;
    __syncthreads();
    if (kt + 1 < kTiles) {
      ap += 64; bp += 64;
      ag0 = *(const half8*)ap; ag1 = *(const half8*)(ap + 8);
      bg0 = *(const half8*)bp; bg1 = *(const half8*)(bp + 8);
    }
    #pragma unroll
    for (int ks = 0; ks < 2; ++ks) {
      half8 af = *(const half8*)&As[16 * w + fr][ks * 32 + fo];
      #pragma unroll
      for (int c = 0; c < 4; ++c) {
        half8 bf = *(const half8*)&Bs[16 * c + fr][ks * 32 + fo];
        acc[c] = __builtin_amdgcn_mfma_f32_16x16x32_f16(af, bf, acc[c], 0, 0, 0);
      }
    }
  }
  int lrow = (l >> 4) * 4, lcol = l & 15;
  #pragma unroll
  for (int c = 0; c < 4; ++c) {
    #pragma unroll
    for (int rr = 0; rr < 4; ++rr) {
      int gm = mt * 64 + 16 * w + lrow + rr;
      int gn = nt * 64 + 16 * c + lcol;
      int ecol = gn + bz * cColOff;
      float vv = acc[c][rr];
      if (bias) vv += bias[ecol];
      vv *= scale;
      if (doRelu) vv = fmaxf(vv, 0.f);
      long oidx = (long)gm * ldc + ecol;
      if (outMode == 0) outF[oidx] = vv;
      else if (outMode == 1) outH[oidx] = (_Float16)vv;
      else atomicAdd(outF + oidx, vv);
    }
  }
}

// ---------------- vfeat = relu(acc + b2): output 0 + fp16 copy ----------------
__global__ __launch_bounds__(256) void k_vfeat(
    const float* __restrict__ vacc, const float* __restrict__ b2,
    float* __restrict__ outF, _Float16* __restrict__ vf16)
{
  int i = blockIdx.x * 256 + threadIdx.x;
  float vv = vacc[i] + b2[i & 511];
  vv = fmaxf(vv, 0.f);
  outF[i] = vv;
  vf16[i] = (_Float16)vv;
}

// ---------------- qk[n,h,d] = sum_j q[n,h*64+j] * Wk[h*64+j][d];  qb = q.bk ----------------
__global__ __launch_bounds__(256) void k_qk(
    const float* __restrict__ qf, const float* __restrict__ Wk,
    const float* __restrict__ bk, float* __restrict__ qk, float* __restrict__ qb)
{
  int n = blockIdx.x, tid = threadIdx.x;
  __shared__ float qs[512];
  qs[tid] = qf[n * 512 + tid];
  qs[tid + 256] = qf[n * 512 + tid + 256];
  __syncthreads();
  #pragma unroll 1
  for (int h = 0; h < 8; ++h) {
    float a0 = 0.f, a1 = 0.f;
    #pragma unroll 8
    for (int j = 0; j < 64; ++j) {
      float qv = qs[h * 64 + j];                 // LDS broadcast
      const float* wr = Wk + (long)(h * 64 + j) * 512;
      a0 = fmaf(qv, wr[tid], a0);                // coalesced
      a1 = fmaf(qv, wr[tid + 256], a1);
    }
    qk[(long)(n * 8 + h) * 512 + tid] = a0;
    qk[(long)(n * 8 + h) * 512 + tid + 256] = a1;
  }
  if (tid < 64) {
    #pragma unroll 1
    for (int h = 0; h < 8; ++h) {
      float pb = qs[h * 64 + tid] * bk[h * 64 + tid];
      #pragma unroll
      for (int m = 1; m < 64; m <<= 1) pb += __shfl_xor(pb, m, 64);
      if (tid == 0) qb[n * 8 + h] = pb;
    }
  }
}

// ---------------- fused streaming attention over t (single pass, no max-sub) ----------------
// grid = N*NSPLIT; each wave streams rows, lane l owns d in {4l..4l+3, 256+4l..256+4l+3}
__global__ __launch_bounds__(256) void k_attn(
    const float* __restrict__ t, const int* __restrict__ tlen,
    const float* __restrict__ qk, const float* __restrict__ qb,
    float* __restrict__ pu, float* __restrict__ pl)
{
  int n  = blockIdx.x >> 3;
  int sp = blockIdx.x & 7;
  int len = tlen[n];
  int chunk = (len + NSPLIT - 1) / NSPLIT;
  int s0 = sp * chunk;
  int s1 = s0 + chunk; if (s1 > len) s1 = len;
  int tid = threadIdx.x, wid = tid >> 6, l = tid & 63;

  const float* qkn = qk + (long)n * 8 * 512;
  f32x4 qlo[8], qhi[8];
  float qbr[8];
  #pragma unroll
  for (int h = 0; h < 8; ++h) {
    qlo[h] = *(const f32x4*)(qkn + h * 512 + 4 * l);
    qhi[h] = *(const f32x4*)(qkn + h * 512 + 256 + 4 * l);
    qbr[h] = qb[n * 8 + h];
  }
  f32x4 ulo[8], uhi[8];
  float lac[8];
  #pragma unroll
  for (int h = 0; h < 8; ++h) {
    ulo[h] = (f32x4){0.f, 0.f, 0.f, 0.f};
    uhi[h] = (f32x4){0.f, 0.f, 0.f, 0.f};
    lac[h] = 0.f;
  }
  const float* tn = t + (long)n * SSEQ * TD;
  int s = s0 + wid;
  f32x4 tlo = (f32x4){0.f,0.f,0.f,0.f}, thi = (f32x4){0.f,0.f,0.f,0.f};
  if (s < s1) {
    tlo = *(const f32x4*)(tn + (long)s * TD + 4 * l);
    thi = *(const f32x4*)(tn + (long)s * TD + 256 + 4 * l);
  }
  for (; s < s1; s += 4) {
    f32x4 clo = tlo, chi = thi;
    int sn = s + 4;
    if (sn < s1) {                               // prefetch next row
      tlo = *(const f32x4*)(tn + (long)sn * TD + 4 * l);
      thi = *(const f32x4*)(tn + (long)sn * TD + 256 + 4 * l);
    }
    float p[8];
    #pragma unroll
    for (int h = 0; h < 8; ++h)
      p[h] = clo[0]*qlo[h][0] + clo[1]*qlo[h][1] + clo[2]*qlo[h][2] + clo[3]*qlo[h][3]
           + chi[0]*qhi[h][0] + chi[1]*qhi[h][1] + chi[2]*qhi[h][2] + chi[3]*qhi[h][3];
    #pragma unroll
    for (int m = 1; m < 64; m <<= 1) {
      #pragma unroll
      for (int h = 0; h < 8; ++h) p[h] += __shfl_xor(p[h], m, 64);
    }
    #pragma unroll
    for (int h = 0; h < 8; ++h) {
      float e = __expf(p[h] + qbr[h]);           // scores are O(0.1): no max-sub needed
      lac[h] += e;
      ulo[h] += e * clo;
      uhi[h] += e * chi;
    }
  }
  // combine 4 waves via LDS
  __shared__ float uc[8][512];
  __shared__ float lc[8];
  for (int i = tid; i < 4096; i += 256) (&uc[0][0])[i] = 0.f;
  if (tid < 8) lc[tid] = 0.f;
  __syncthreads();
  #pragma unroll
  for (int h = 0; h < 8; ++h) {
    atomicAdd(&uc[h][4 * l + 0], ulo[h][0]);
    atomicAdd(&uc[h][4 * l + 1], ulo[h][1]);
    atomicAdd(&uc[h][4 * l + 2], ulo[h][2]);
    atomicAdd(&uc[h][4 * l + 3], ulo[h][3]);
    atomicAdd(&uc[h][256 + 4 * l + 0], uhi[h][0]);
    atomicAdd(&uc[h][256 + 4 * l + 1], uhi[h][1]);
    atomicAdd(&uc[h][256 + 4 * l + 2], uhi[h][2]);
    atomicAdd(&uc[h][256 + 4 * l + 3], uhi[h][3]);
  }
  if (l == 0) {
    #pragma unroll
    for (int h = 0; h < 8; ++h) atomicAdd(&lc[h], lac[h]);
  }
  __syncthreads();
  float* po = pu + (long)(n * 8 + sp) * 4096;
  for (int i = tid; i < 4096; i += 256) po[i] = (&uc[0][0])[i];
  if (tid < 8) pl[(n * 8 + sp) * 8 + tid] = lc[tid];
}

// ---------------- combine splits, normalize, emit fp16 [h][n][512] ----------------
__global__ __launch_bounds__(256) void k_norm(
    const float* __restrict__ pu, const float* __restrict__ pl,
    _Float16* __restrict__ un16)
{
  int n = blockIdx.x, tid = threadIdx.x;
  __shared__ float linv[8];
  if (tid < 8) {
    float L = 0.f;
    for (int sp = 0; sp < 8; ++sp) L += pl[(n * 8 + sp) * 8 + tid];
    linv[tid] = 1.f / L;
  }
  __syncthreads();
  for (int i = tid; i < 4096; i += 256) {
    int h = i >> 9, d = i & 511;
    float sacc = 0.f;
    #pragma unroll
    for (int sp = 0; sp < 8; ++sp) sacc += pu[(long)(n * 8 + sp) * 4096 + i];
    un16[(long)h * 65536 + n * 512 + d] = (_Float16)(sacc * linv[h]);
  }
}

extern "C" void kernel_launch(void* const* d_in, const int* in_sizes, int n_in,
                              void* d_out, int out_size, void* d_ws, size_t ws_size,
                              hipStream_t stream)
{
  const float* v    = (const float*)d_in[0];
  const float* t    = (const float*)d_in[1];
  const int*   tlen = (const int*)d_in[2];
  const float* b1   = (const float*)d_in[4];
  const float* b2   = (const float*)d_in[6];
  const float* Wk   = (const float*)d_in[8];
  const float* bq   = (const float*)d_in[10];
  const float* bk   = (const float*)d_in[11];
  const float* bv   = (const float*)d_in[12];
  const float* bo   = (const float*)d_in[14];
  float* out = (float*)d_out;

  // ---- workspace layout (fp16 region then fp32 region), ~33.3 MB total ----
  _Float16* hb   = (_Float16*)d_ws;
  _Float16* v16  = hb;                  // 1179648
  _Float16* w1h  = hb + 1179648l;       // 393216
  _Float16* w2h  = hb + 1572864l;       // 3145728
  _Float16* wqh  = hb + 4718592l;       // 262144
  _Float16* wvh  = hb + 4980736l;       // 262144
  _Float16* woh  = hb + 5242880l;       // 262144
  _Float16* x16  = hb + 5505024l;       // 786432
  _Float16* vf16 = hb + 6291456l;       // 65536
  _Float16* ctx16= hb + 6356992l;       // 65536
  _Float16* un16 = hb + 6422528l;       // 524288
  float* fb   = (float*)(hb + 6946816l);
  float* vacc = fb;                     // 65536
  float* qf   = fb + 65536l;            // 65536
  float* qk   = fb + 131072l;           // 524288
  float* qb   = fb + 655360l;           // 1024
  float* pl   = fb + 656384l;           // 8192
  float* pu   = fb + 664576l;           // 4194304

  hipMemsetAsync(vacc, 0, 65536 * sizeof(float), stream);
  k_cvt<<<5376, 256, 0, stream>>>((const float*)d_in[0], (const float*)d_in[3],
                                  (const float*)d_in[5], (const float*)d_in[7],
                                  (const float*)d_in[9], (const float*)d_in[13],
                                  v16, w1h, w2h, wqh, wvh, woh);
  // fc1: [1536x768]x[512x768]^T -> relu -> x16 [1536x512]
  k_gemm<<<dim3(192, 1, 1), 256, 0, stream>>>(v16, 768, 0, w1h, 768, 0,
      b1, 1.f, 1, 1, nullptr, x16, 512, 0, 24, 12);
  // fc2 split-K(8): [128x6144]x[512x6144]^T -> atomic fp32 -> vacc
  k_gemm<<<dim3(16, 8, 1), 256, 0, stream>>>(x16, 6144, 0, w2h, 6144, 0,
      nullptr, 1.f, 0, 2, vacc, nullptr, 512, 0, 2, 12);
  k_vfeat<<<256, 256, 0, stream>>>(vacc, b2, out, vf16);
  // q = (vfeat @ Wq^T + bq) * 0.125
  k_gemm<<<dim3(16, 1, 1), 256, 0, stream>>>(vf16, 512, 0, wqh, 512, 0,
      bq, 0.125f, 0, 0, qf, nullptr, 512, 0, 2, 8);
  k_qk<<<128, 256, 0, stream>>>(qf, Wk, bk, qk, qb);
  k_attn<<<NB * NSPLIT, 256, 0, stream>>>(t, tlen, qk, qb, pu, pl);
  k_norm<<<128, 256, 0, stream>>>(pu, pl, un16);
  // ctx[n, h*64+j] = un16[h] @ Wv_head^T + bv  (batched over h via grid.z)
  k_gemm<<<dim3(2, 1, 8), 256, 0, stream>>>(un16, 512, 65536, wvh, 512, 32768,
      bv, 1.f, 0, 1, nullptr, ctx16, 512, 64, 2, 8);
  // attn_out = ctx @ Wo^T + bo -> output 1
  k_gemm<<<dim3(16, 1, 1), 256, 0, stream>>>(ctx16, 512, 0, woh, 512, 0,
      bo, 1.f, 0, 0, out + 65536, nullptr, 512, 0, 2, 8);
}

// Round 2
// 480.262 us; speedup vs baseline: 1.2342x; 1.2342x over previous
//
#include <hip/hip_runtime.h>

#define NB 128
#define SSEQ 1024
#define TD 512
#define NSPLIT 16

typedef _Float16 half8 __attribute__((ext_vector_type(8)));
typedef _Float16 half4 __attribute__((ext_vector_type(4)));
typedef _Float16 half2v __attribute__((ext_vector_type(2)));
typedef float f32x4 __attribute__((ext_vector_type(4)));
typedef float f32x2 __attribute__((ext_vector_type(2)));

// ---------------- K0: fp32 -> fp16 conversions (fused, vec4) ----------------
__global__ __launch_bounds__(256) void k_cvt(
    const float* __restrict__ v, const float* __restrict__ w1,
    const float* __restrict__ w2, const float* __restrict__ wq,
    const float* __restrict__ wv, const float* __restrict__ wo,
    _Float16* __restrict__ v16, _Float16* __restrict__ w1h,
    _Float16* __restrict__ w2h, _Float16* __restrict__ wqh,
    _Float16* __restrict__ wvh, _Float16* __restrict__ woh)
{
  int i = blockIdx.x * 256 + threadIdx.x;   // vec4 index
  const float* src; _Float16* dst; long j;
  if      (i < 294912)  { src = v;  dst = v16; j = i; }
  else if (i < 393216)  { src = w1; dst = w1h; j = i - 294912; }
  else if (i < 1179648) { src = w2; dst = w2h; j = i - 393216; }
  else if (i < 1245184) { src = wq; dst = wqh; j = i - 1179648; }
  else if (i < 1310720) { src = wv; dst = wvh; j = i - 1245184; }
  else if (i < 1376256) { src = wo; dst = woh; j = i - 1310720; }
  else return;
  f32x4 x = *(const f32x4*)(src + 4 * j);
  *(half4*)(dst + 4 * j) = __builtin_convertvector(x, half4);
}

// ---------------- generic NT GEMM, fp16 MFMA, fp32 accum ----------------
// C[m][n] = sum_k A[m][k]*B[n][k]; 64x64 tile, 4 waves.
// outMode: 0 = fp32 store, 1 = fp16 store, 2 = fp32 store to outF + sp*oSplit (split-K partials)
__global__ __launch_bounds__(256) void k_gemm(
    const _Float16* __restrict__ A, int lda, long aSZ,
    const _Float16* __restrict__ B, int ldb, long bSZ,
    const float* __restrict__ bias, float scale, int doRelu, int outMode,
    float* __restrict__ outF, _Float16* __restrict__ outH,
    int ldc, int cColOff, int mtiles, int kTiles, long oSplit)
{
  __shared__ _Float16 As[64][72];
  __shared__ _Float16 Bs[64][72];
  int mt = blockIdx.x % mtiles, nt = blockIdx.x / mtiles;
  int sp = blockIdx.y, bz = blockIdx.z;
  int tid = threadIdx.x;
  int r = tid >> 2, kq = (tid & 3) * 16;
  int w = tid >> 6, l = tid & 63;
  const _Float16* Ab = A + (long)bz * aSZ + (long)(mt * 64) * lda + (long)sp * kTiles * 64;
  const _Float16* Bb = B + (long)bz * bSZ + (long)(nt * 64) * ldb + (long)sp * kTiles * 64;
  const _Float16* ap = Ab + (long)r * lda + kq;
  const _Float16* bp = Bb + (long)r * ldb + kq;
  half8 ag0 = *(const half8*)ap, ag1 = *(const half8*)(ap + 8);
  half8 bg0 = *(const half8*)bp, bg1 = *(const half8*)(bp + 8);
  f32x4 acc[4];
  #pragma unroll
  for (int c = 0; c < 4; ++c) acc[c] = (f32x4){0.f, 0.f, 0.f, 0.f};
  int fr = l & 15, fo = (l >> 4) * 8;
  for (int kt = 0; kt < kTiles; ++kt) {
    __syncthreads();
    *(half8*)&As[r][kq] = ag0; *(half8*)&As[r][kq + 8] = ag1;
    *(half8*)&Bs[r][kq] = bg0; *(half8*)&Bs[r][kq + 8] = bg1;
    __syncthreads();
    if (kt + 1 < kTiles) {
      ap += 64; bp += 64;
      ag0 = *(const half8*)ap; ag1 = *(const half8*)(ap + 8);
      bg0 = *(const half8*)bp; bg1 = *(const half8*)(bp + 8);
    }
    #pragma unroll
    for (int ks = 0; ks < 2; ++ks) {
      half8 af = *(const half8*)&As[16 * w + fr][ks * 32 + fo];
      #pragma unroll
      for (int c = 0; c < 4; ++c) {
        half8 bf = *(const half8*)&Bs[16 * c + fr][ks * 32 + fo];
        acc[c] = __builtin_amdgcn_mfma_f32_16x16x32_f16(af, bf, acc[c], 0, 0, 0);
      }
    }
  }
  int lrow = (l >> 4) * 4, lcol = l & 15;
  #pragma unroll
  for (int c = 0; c < 4; ++c) {
    #pragma unroll
    for (int rr = 0; rr < 4; ++rr) {
      int gm = mt * 64 + 16 * w + lrow + rr;
      int gn = nt * 64 + 16 * c + lcol;
      int ecol = gn + bz * cColOff;
      float vv = acc[c][rr];
      if (bias) vv += bias[ecol];
      vv *= scale;
      if (doRelu) vv = fmaxf(vv, 0.f);
      long oidx = (long)gm * ldc + ecol;
      if (outMode == 0) outF[oidx] = vv;
      else if (outMode == 1) outH[oidx] = (_Float16)vv;
      else outF[oidx + (long)sp * oSplit] = vv;
    }
  }
}

// ---------------- vfeat = relu(sum_splits + b2): output 0 + fp16 copy ----------------
__global__ __launch_bounds__(256) void k_vfeat(
    const float* __restrict__ vacc, const float* __restrict__ b2,
    float* __restrict__ outF, _Float16* __restrict__ vf16)
{
  int i = blockIdx.x * 256 + threadIdx.x;
  float vv = b2[i & 511];
  #pragma unroll
  for (int sp = 0; sp < 16; ++sp) vv += vacc[sp * 65536 + i];
  vv = fmaxf(vv, 0.f);
  outF[i] = vv;
  vf16[i] = (_Float16)vv;
}

// ---------------- qk16[n,h,d] = sum_j q[n,h*64+j]*Wk[h*64+j][d] (h<8; h=8..15 zero); qb = q.bk ----
__global__ __launch_bounds__(256) void k_qk(
    const float* __restrict__ qacc, const float* __restrict__ bq,
    const float* __restrict__ Wk, const float* __restrict__ bk,
    _Float16* __restrict__ qk16, float* __restrict__ qb)
{
  int n = blockIdx.x, tid = threadIdx.x;
  __shared__ float qs[512];
  #pragma unroll
  for (int o = 0; o < 2; ++o) {
    int d = tid + o * 256;
    float q0 = qacc[n * 512 + d] + qacc[65536 + n * 512 + d]
             + qacc[131072 + n * 512 + d] + qacc[196608 + n * 512 + d];
    qs[d] = (q0 + bq[d]) * 0.125f;
  }
  __syncthreads();
  _Float16* qn = qk16 + (long)n * 8192;
  #pragma unroll 1
  for (int h = 0; h < 8; ++h) {
    float a0 = 0.f, a1 = 0.f;
    #pragma unroll 8
    for (int j = 0; j < 64; ++j) {
      float qv = qs[h * 64 + j];
      const float* wr = Wk + (long)(h * 64 + j) * 512;
      a0 = fmaf(qv, wr[tid], a0);
      a1 = fmaf(qv, wr[tid + 256], a1);
    }
    qn[h * 512 + tid] = (_Float16)a0;
    qn[h * 512 + tid + 256] = (_Float16)a1;
  }
  #pragma unroll
  for (int h = 8; h < 16; ++h) {
    qn[h * 512 + tid] = (_Float16)0.f;
    qn[h * 512 + tid + 256] = (_Float16)0.f;
  }
  if (tid < 64) {
    #pragma unroll 1
    for (int h = 0; h < 8; ++h) {
      float pb = qs[h * 64 + tid] * bk[h * 64 + tid];
      #pragma unroll
      for (int m = 1; m < 64; m <<= 1) pb += __shfl_xor(pb, m, 64);
      if (tid == 0) qb[n * 8 + h] = pb;
    }
  }
}

// ---------------- fused streaming attention: LDS-staged tiles, MFMA scores, VALU PV ----------
// grid = N*NSPLIT blocks of 256. Supertile = 32 rows. Results atomically accumulated into pu/pl.
__global__ __launch_bounds__(256, 4) void k_attn(
    const float* __restrict__ t, const int* __restrict__ tlen,
    const _Float16* __restrict__ qk16, const float* __restrict__ qb,
    float* __restrict__ pu, float* __restrict__ pl)
{
  int n = blockIdx.x >> 4, sp = blockIdx.x & 15;
  int len = tlen[n];
  int chunk = (len + NSPLIT - 1) / NSPLIT;
  int s0 = sp * chunk;
  int s1 = s0 + chunk; if (s1 > len) s1 = len;
  if (s0 >= s1) return;
  int tid = threadIdx.x, wid = tid >> 6, l = tid & 63;

  __shared__ __align__(16) _Float16 ts[32][520];   // fp16 tile, row stride 1040B (16B-aligned)
  __shared__ __align__(16) float ws[32][8];        // softmax-numerator weights
  __shared__ float lred[8];

  const _Float16* qn = qk16 + (long)n * 8192;
  int fr = l & 15, fo = (l >> 4) * 8;
  half8 qfrag[16];                                  // B-operand fragments, 64 VGPRs
  #pragma unroll
  for (int kt = 0; kt < 16; ++kt)
    qfrag[kt] = *(const half8*)(qn + fr * 512 + kt * 32 + fo);
  float qbr = (fr < 8) ? qb[n * 8 + fr] : 0.f;

  f32x2 u[8];
  #pragma unroll
  for (int h = 0; h < 8; ++h) u[h] = (f32x2){0.f, 0.f};
  float lac = 0.f;
  if (tid < 8) lred[tid] = 0.f;

  const float* tn = t + (long)n * SSEQ * TD;
  int col0 = 128 * wid + 2 * l;                     // PV: wave-owned d range, lane owns 2

  for (int base = s0; base < s1; base += 32) {
    __syncthreads();
    // ---- stage 32 rows fp32->fp16 into LDS (coalesced, 2-chunk pipeline) ----
    {
      f32x4 a0, a1, b0, b1;
      auto ld = [&](int c, f32x4& x0, f32x4& x1) {
        int sg = base + c * 4 + wid;                // wave-uniform row
        if (sg < s1) {
          const float* p = tn + (long)sg * TD;
          x0 = *(const f32x4*)(p + 4 * l);          // first 1KB of row
          x1 = *(const f32x4*)(p + 256 + 4 * l);    // second 1KB
        } else {
          x0 = (f32x4){0.f,0.f,0.f,0.f}; x1 = (f32x4){0.f,0.f,0.f,0.f};
        }
      };
      ld(0, a0, a1); ld(1, b0, b1);
      #pragma unroll
      for (int c = 0; c < 8; c += 2) {
        half4 h0 = __builtin_convertvector(a0, half4);
        half4 h1 = __builtin_convertvector(a1, half4);
        int row = c * 4 + wid;
        if (c + 2 < 8) ld(c + 2, a0, a1);
        *(half4*)&ts[row][4 * l] = h0;
        *(half4*)&ts[row][256 + 4 * l] = h1;
        half4 g0 = __builtin_convertvector(b0, half4);
        half4 g1 = __builtin_convertvector(b1, half4);
        int row2 = c * 4 + 4 + wid;
        if (c + 3 < 8) ld(c + 3, b0, b1);
        *(half4*)&ts[row2][4 * l] = g0;
        *(half4*)&ts[row2][256 + 4 * l] = g1;
      }
    }
    __syncthreads();
    // ---- scores: waves 0,1 via MFMA; D col = head (fr), row = s_local ----
    if (wid < 2) {
      f32x4 acc = (f32x4){0.f, 0.f, 0.f, 0.f};
      #pragma unroll
      for (int kt = 0; kt < 16; ++kt) {
        half8 af = *(const half8*)&ts[16 * wid + fr][kt * 32 + fo];
        acc = __builtin_amdgcn_mfma_f32_16x16x32_f16(af, qfrag[kt], acc, 0, 0, 0);
      }
      #pragma unroll
      for (int r = 0; r < 4; ++r) {
        int sl = 16 * wid + (l >> 4) * 4 + r;
        float wv = 0.f;
        if (fr < 8 && base + sl < s1) wv = __expf(acc[r] + qbr);
        if (fr < 8) ws[sl][fr] = wv;
        lac += wv;
      }
    }
    __syncthreads();
    // ---- PV: all 4 waves, d-split; w broadcast from LDS ----
    #pragma unroll 4
    for (int r = 0; r < 32; ++r) {
      f32x4 wa = *(const f32x4*)&ws[r][0];
      f32x4 wb = *(const f32x4*)&ws[r][4];
      half2v tv = *(const half2v*)&ts[r][col0];
      f32x2 tp = { (float)tv[0], (float)tv[1] };
      u[0] += wa[0] * tp; u[1] += wa[1] * tp;
      u[2] += wa[2] * tp; u[3] += wa[3] * tp;
      u[4] += wb[0] * tp; u[5] += wb[1] * tp;
      u[6] += wb[2] * tp; u[7] += wb[3] * tp;
    }
  }
  // ---- accumulate into global (zeroed) partials ----
  float* pn = pu + (long)n * 4096;
  #pragma unroll
  for (int h = 0; h < 8; ++h) {
    atomicAdd(&pn[h * 512 + col0], u[h][0]);
    atomicAdd(&pn[h * 512 + col0 + 1], u[h][1]);
  }
  if (wid < 2 && fr < 8) atomicAdd(&lred[fr], lac);
  __syncthreads();
  if (tid < 8) atomicAdd(&pl[n * 8 + tid], lred[tid]);
}

// ---------------- normalize, emit fp16 [h][n][512] ----------------
__global__ __launch_bounds__(256) void k_norm(
    const float* __restrict__ pu, const float* __restrict__ pl,
    _Float16* __restrict__ un16)
{
  int n = blockIdx.x, tid = threadIdx.x;
  __shared__ float linv[8];
  if (tid < 8) linv[tid] = 1.f / pl[n * 8 + tid];
  __syncthreads();
  for (int i = tid; i < 4096; i += 256) {
    int h = i >> 9, d = i & 511;
    float sacc = pu[(long)n * 4096 + i];
    un16[(long)h * 65536 + n * 512 + d] = (_Float16)(sacc * linv[h]);
  }
}

extern "C" void kernel_launch(void* const* d_in, const int* in_sizes, int n_in,
                              void* d_out, int out_size, void* d_ws, size_t ws_size,
                              hipStream_t stream)
{
  const float* t    = (const float*)d_in[1];
  const int*   tlen = (const int*)d_in[2];
  const float* b1   = (const float*)d_in[4];
  const float* b2   = (const float*)d_in[6];
  const float* Wk   = (const float*)d_in[8];
  const float* bq   = (const float*)d_in[10];
  const float* bk   = (const float*)d_in[11];
  const float* bv   = (const float*)d_in[12];
  const float* bo   = (const float*)d_in[14];
  float* out = (float*)d_out;

  // ---- workspace layout: fp16 region then fp32 region (~23.3 MB) ----
  _Float16* hb   = (_Float16*)d_ws;
  _Float16* v16  = hb;                  // 1179648
  _Float16* w1h  = hb + 1179648l;       // 393216
  _Float16* w2h  = hb + 1572864l;       // 3145728
  _Float16* wqh  = hb + 4718592l;       // 262144
  _Float16* wvh  = hb + 4980736l;       // 262144
  _Float16* woh  = hb + 5242880l;       // 262144
  _Float16* x16  = hb + 5505024l;       // 786432
  _Float16* vf16 = hb + 6291456l;       // 65536
  _Float16* ctx16= hb + 6356992l;       // 65536
  _Float16* un16 = hb + 6422528l;       // 524288
  _Float16* qk16 = hb + 6946816l;       // 1048576  [n][16 heads][512]
  float* fb   = (float*)(hb + 7995392l);
  float* vacc = fb;                     // 16*65536 = 1048576
  float* qacc = fb + 1048576l;          // 4*65536 = 262144
  float* qb   = fb + 1310720l;          // 1024
  float* pu   = fb + 1311744l;          // 524288
  float* pl   = fb + 1836032l;          // 1024

  hipMemsetAsync(pu, 0, (524288l + 1024l) * sizeof(float), stream);
  k_cvt<<<5376, 256, 0, stream>>>((const float*)d_in[0], (const float*)d_in[3],
                                  (const float*)d_in[5], (const float*)d_in[7],
                                  (const float*)d_in[9], (const float*)d_in[13],
                                  v16, w1h, w2h, wqh, wvh, woh);
  // fc1: [1536x768]x[512x768]^T -> relu -> x16 [1536x512]
  k_gemm<<<dim3(192, 1, 1), 256, 0, stream>>>(v16, 768, 0, w1h, 768, 0,
      b1, 1.f, 1, 1, nullptr, x16, 512, 0, 24, 12, 0);
  // fc2 split-K(16): [128x6144]x[512x6144]^T -> partials -> vacc[16][65536]
  k_gemm<<<dim3(16, 16, 1), 256, 0, stream>>>(x16, 6144, 0, w2h, 6144, 0,
      nullptr, 1.f, 0, 2, vacc, nullptr, 512, 0, 2, 6, 65536);
  k_vfeat<<<256, 256, 0, stream>>>(vacc, b2, out, vf16);
  // q partials split-K(4): [128x512]x[512x512]^T -> qacc[4][65536] (bias+scale applied in k_qk)
  k_gemm<<<dim3(16, 4, 1), 256, 0, stream>>>(vf16, 512, 0, wqh, 512, 0,
      nullptr, 1.f, 0, 2, qacc, nullptr, 512, 0, 2, 2, 65536);
  k_qk<<<128, 256, 0, stream>>>(qacc, bq, Wk, bk, qk16, qb);
  k_attn<<<NB * NSPLIT, 256, 0, stream>>>(t, tlen, qk16, qb, pu, pl);
  k_norm<<<128, 256, 0, stream>>>(pu, pl, un16);
  // ctx[n, h*64+j] = un16[h] @ Wv_head^T + bv (batched over h via grid.z)
  k_gemm<<<dim3(2, 1, 8), 256, 0, stream>>>(un16, 512, 65536, wvh, 512, 32768,
      bv, 1.f, 0, 1, nullptr, ctx16, 512, 64, 2, 8, 0);
  // attn_out = ctx @ Wo^T + bo -> output 1
  k_gemm<<<dim3(16, 1, 1), 256, 0, stream>>>(ctx16, 512, 0, woh, 512, 0,
      bo, 1.f, 0, 0, out + 65536, nullptr, 512, 0, 2, 8, 0);
}